// Round 2
// baseline (784.437 us; speedup 1.0000x reference)
//
#include <hip/hip_runtime.h>
#include <hip/hip_bf16.h>

typedef __bf16 bf16;
typedef __bf16 bf16x8 __attribute__((ext_vector_type(8)));
typedef float f32x4 __attribute__((ext_vector_type(4)));

#define N4 4096
#define CCH 384

// ---------------------------------------------------------------------------
// Input dtype detection: f32 data read as dwords has random bits in [14:7]
// (low bf16 half's exponent field) -> ~16% "plausible bf16 pair"; real bf16
// pair data -> ~100%. Writes flag: 1 = inputs are bf16, 0 = inputs are f32.
// ---------------------------------------------------------------------------
__global__ void detect_kernel(const unsigned int* __restrict__ w, int* flag)
{
    if (threadIdx.x == 0 && blockIdx.x == 0) {
        int cnt = 0;
        for (int i = 0; i < 256; i++) {
            unsigned v = w[i];
            int elo = (v >> 7) & 0xFF, ehi = (v >> 23) & 0xFF;
            bool lo_ok = (elo >= 100 && elo <= 140) || ((v & 0xFFFFu) == 0);
            bool hi_ok = (ehi >= 100 && ehi <= 140) || ((v >> 16) == 0);
            if (lo_ok && hi_ok) cnt++;
        }
        *flag = (cnt >= 200) ? 1 : 0;
    }
}

// canonicalize one input tensor to bf16, branching on runtime dtype flag
__global__ __launch_bounds__(256) void convert_kernel(
    const void* __restrict__ src, bf16* __restrict__ dst, long n,
    const int* __restrict__ flag)
{
    long i = (long)blockIdx.x * 256 + threadIdx.x;
    if (i >= n) return;
    if (*flag) dst[i] = ((const bf16*)src)[i];
    else       dst[i] = (bf16)((const float*)src)[i];
}

// ---------------------------------------------------------------------------
// Generic bf16 MFMA GEMM: out[b][m][n] = sum_k W[m][k] * X[b][k][n] (+bias[m])
// W: (M,K) row-major bf16. X: per-batch (K,4096), n-contiguous. out: (M,4096).
// Block = 256 threads = 4 waves; tile 64x64, BK=32. Wave w -> 32x32 quadrant,
// 2x2 MFMA 16x16x32 tiles. Both fragments ds_read_b128. M%64==0, K%32==0.
// If outFlag != nullptr and *outFlag == 0, output is written as f32.
// ---------------------------------------------------------------------------
__global__ __launch_bounds__(256) void gemm_bf16_kernel(
    const bf16* __restrict__ Wg, const bf16* __restrict__ Xg,
    const bf16* __restrict__ bias, void* __restrict__ Og,
    int K, long xStride, long oStride, const int* __restrict__ outFlag)
{
    constexpr int LDP = 40;              // row stride (bf16): 80B, 16B-aligned
    __shared__ bf16 Wt[64 * LDP];
    __shared__ bf16 Xt[64 * LDP];
    const int t = threadIdx.x;
    const int b = blockIdx.z;
    const int mBase = blockIdx.y << 6;
    const int nBase = blockIdx.x << 6;
    const bf16* Xb = Xg + (long)b * xStride;
    const int lane = t & 63, wv = t >> 6;
    const int wm = (wv >> 1) << 5, wn = (wv & 1) << 5;
    const int lr = lane & 15, qd = lane >> 4;
    const int wlm = t >> 2, wlk = (t & 3) << 3;       // W tile: 64 rows x 32k
    const int xln = t & 63, xlk = (t >> 6) << 3;      // X tile: 64 n x 32k (transposed)

    f32x4 acc[2][2] = {};

    for (int k0 = 0; k0 < K; k0 += 32) {
        bf16x8 wvv = *(const bf16x8*)(Wg + (long)(mBase + wlm) * K + k0 + wlk);
        const bf16* xp = Xb + (long)(k0 + xlk) * N4 + nBase + xln;
        bf16x8 xvv;
        #pragma unroll
        for (int j = 0; j < 8; j++) xvv[j] = xp[(long)j * N4];

        __syncthreads();   // previous iter's LDS reads done
        *(bf16x8*)(&Wt[wlm * LDP + wlk]) = wvv;
        *(bf16x8*)(&Xt[xln * LDP + xlk]) = xvv;
        __syncthreads();

        bf16x8 af[2], bfr[2];
        #pragma unroll
        for (int i = 0; i < 2; i++) {
            af[i]  = *(const bf16x8*)(&Wt[(wm + i * 16 + lr) * LDP + qd * 8]);
            bfr[i] = *(const bf16x8*)(&Xt[(wn + i * 16 + lr) * LDP + qd * 8]);
        }
        #pragma unroll
        for (int i = 0; i < 2; i++)
            #pragma unroll
            for (int j = 0; j < 2; j++)
                acc[i][j] = __builtin_amdgcn_mfma_f32_16x16x32_bf16(
                    af[i], bfr[j], acc[i][j], 0, 0, 0);
    }

    const bool f32o = outFlag ? (*outFlag == 0) : false;
    #pragma unroll
    for (int i = 0; i < 2; i++)
        #pragma unroll
        for (int j = 0; j < 2; j++)
            #pragma unroll
            for (int r = 0; r < 4; r++) {
                int row = mBase + wm + i * 16 + qd * 4 + r;   // C/D: row=quad*4+reg
                int col = nBase + wn + j * 16 + lr;           //      col=lane&15
                float v = acc[i][j][r];
                if (bias) v += (float)bias[row];
                long oi = (long)b * oStride + (long)row * N4 + col;
                if (f32o) ((float*)Og)[oi] = v;
                else      ((bf16*)Og)[oi] = (bf16)v;
            }
}

// ---------------------------------------------------------------------------
// Row inverse L2 norms for q,k channels: invn[b*768+c] = 1/max(||row||,1e-12)
// ---------------------------------------------------------------------------
__global__ __launch_bounds__(256) void rownorm_kernel(
    const bf16* __restrict__ qkv, float* __restrict__ invn)
{
    const int c = blockIdx.x, b = blockIdx.y;   // c in [0,768)
    const bf16* p = qkv + (long)b * 3 * CCH * N4 + (long)c * N4;
    float s = 0.f;
    for (int i = threadIdx.x; i < N4; i += 256) { float v = (float)p[i]; s += v * v; }
    #pragma unroll
    for (int o = 32; o; o >>= 1) s += __shfl_down(s, o, 64);
    __shared__ float red[4];
    if ((threadIdx.x & 63) == 0) red[threadIdx.x >> 6] = s;
    __syncthreads();
    if (threadIdx.x == 0) {
        float tot = red[0] + red[1] + red[2] + red[3];
        invn[b * 768 + c] = 1.0f / fmaxf(sqrtf(tot), 1e-12f);
    }
}

// ---------------------------------------------------------------------------
// Attention logits partials: part[bh][slot][48x48], slot = kc*4+wave covers
// 128 n-positions; fragments load directly from global (k(=n)-contiguous).
// ---------------------------------------------------------------------------
__global__ __launch_bounds__(256) void attn_logits_kernel(
    const bf16* __restrict__ qkv, float* __restrict__ part)
{
    const int kc = blockIdx.x;          // 0..7
    const int bh = blockIdx.y;          // 0..63
    const int b = bh >> 3, h = bh & 7;
    const int t = threadIdx.x, lane = t & 63, wv = t >> 6;
    const int lr = lane & 15, qd = lane >> 4;
    const bf16* qb = qkv + (long)b * 3 * CCH * N4 + (long)h * 48 * N4;
    const bf16* kb = qb + (long)CCH * N4;
    const int k0b = (kc * 4 + wv) * 128;
    f32x4 acc[3][3] = {};
    for (int s = 0; s < 4; s++) {
        const int k0 = k0b + s * 32;
        bf16x8 a[3], bb[3];
        #pragma unroll
        for (int i = 0; i < 3; i++) {
            a[i]  = *(const bf16x8*)(qb + (long)(i * 16 + lr) * N4 + k0 + qd * 8);
            bb[i] = *(const bf16x8*)(kb + (long)(i * 16 + lr) * N4 + k0 + qd * 8);
        }
        #pragma unroll
        for (int i = 0; i < 3; i++)
            #pragma unroll
            for (int j = 0; j < 3; j++)
                acc[i][j] = __builtin_amdgcn_mfma_f32_16x16x32_bf16(
                    a[i], bb[j], acc[i][j], 0, 0, 0);
    }
    float* pp = part + ((long)bh * 32 + kc * 4 + wv) * 2304;
    #pragma unroll
    for (int i = 0; i < 3; i++)
        #pragma unroll
        for (int j = 0; j < 3; j++)
            #pragma unroll
            for (int r = 0; r < 4; r++)
                pp[(i * 16 + qd * 4 + r) * 48 + j * 16 + lr] = acc[i][j][r];
}

// ---------------------------------------------------------------------------
// Sum partials, scale by invq*invk*temperature, softmax over e -> attn (f32)
// ---------------------------------------------------------------------------
__global__ __launch_bounds__(256) void attn_softmax_kernel(
    const float* __restrict__ part, const float* __restrict__ invn,
    const bf16* __restrict__ temp, float* __restrict__ attn)
{
    __shared__ float sl[2304];
    const int bh = blockIdx.x, b = bh >> 3, h = bh & 7;
    const int t = threadIdx.x;
    const float tmp = (float)temp[h];
    for (int idx = t; idx < 2304; idx += 256) {
        float s = 0.f;
        for (int p = 0; p < 32; p++) s += part[((long)bh * 32 + p) * 2304 + idx];
        int d = idx / 48, e = idx - d * 48;
        s *= invn[b * 768 + h * 48 + d] * invn[b * 768 + 384 + h * 48 + e] * tmp;
        sl[idx] = s;
    }
    __syncthreads();
    if (t < 48) {
        float m = -1e30f;
        #pragma unroll
        for (int e = 0; e < 48; e++) m = fmaxf(m, sl[t * 48 + e]);
        float ex[48]; float sum = 0.f;
        #pragma unroll
        for (int e = 0; e < 48; e++) { ex[e] = expf(sl[t * 48 + e] - m); sum += ex[e]; }
        float inv = 1.0f / sum;
        #pragma unroll
        for (int e = 0; e < 48; e++) attn[(long)bh * 2304 + t * 48 + e] = ex[e] * inv;
    }
}

// ---------------------------------------------------------------------------
// at[b][h*48+d][n] = sum_e attn[d][e] * v[b][h*48+e][n]
// ---------------------------------------------------------------------------
__global__ __launch_bounds__(256) void attn_apply_kernel(
    const float* __restrict__ attn, const bf16* __restrict__ qkv,
    bf16* __restrict__ at)
{
    __shared__ float sa[2304];
    const int bh = blockIdx.y, b = bh >> 3, h = bh & 7;
    const int t = threadIdx.x;
    for (int i = t; i < 2304; i += 256) sa[i] = attn[(long)bh * 2304 + i];
    __syncthreads();
    const int n = blockIdx.x * 256 + t;
    const bf16* vb = qkv + (long)b * 3 * CCH * N4 + (long)(2 * CCH + h * 48) * N4;
    float acc[48];
    #pragma unroll
    for (int d = 0; d < 48; d++) acc[d] = 0.f;
    for (int e = 0; e < 48; e++) {
        float vv = (float)vb[(long)e * N4 + n];
        #pragma unroll
        for (int d = 0; d < 48; d++) acc[d] += sa[d * 48 + e] * vv;
    }
    bf16* ab = at + (long)b * CCH * N4 + (long)h * 48 * N4 + n;
    #pragma unroll
    for (int d = 0; d < 48; d++) ab[(long)d * N4] = (bf16)acc[d];
}

// ---------------------------------------------------------------------------
// Depthwise SxS conv, dilation/pad, H=W=64. grid (n/256, C, B)
// ---------------------------------------------------------------------------
__global__ __launch_bounds__(256) void dw_kernel(
    const bf16* __restrict__ in, const bf16* __restrict__ wt,
    const bf16* __restrict__ bias, bf16* __restrict__ outp,
    int S, int dil, int pad)
{
    const int Cc = gridDim.y;
    const int b = blockIdx.z, c = blockIdx.y;
    const int n = blockIdx.x * 256 + threadIdx.x;
    const int y = n >> 6, x = n & 63;
    const bf16* ip = in + ((long)b * Cc + c) * N4;
    float acc = (float)bias[c];
    for (int i = 0; i < S; i++) {
        int yy = y + i * dil - pad;
        if (yy < 0 || yy >= 64) continue;
        for (int j = 0; j < S; j++) {
            int xx = x + j * dil - pad;
            if (xx < 0 || xx >= 64) continue;
            acc += (float)wt[(c * S + i) * S + j] * (float)ip[yy * 64 + xx];
        }
    }
    outp[((long)b * Cc + c) * N4 + n] = (bf16)acc;
}

// mean over spatial: out[b*C + c], grid (C, B)
__global__ __launch_bounds__(256) void mean_kernel(
    const bf16* __restrict__ in, float* __restrict__ outp)
{
    const int Cc = gridDim.x;
    const int c = blockIdx.x, b = blockIdx.y;
    const bf16* p = in + ((long)b * Cc + c) * N4;
    float s = 0.f;
    for (int i = threadIdx.x; i < N4; i += 256) s += (float)p[i];
    #pragma unroll
    for (int o = 32; o; o >>= 1) s += __shfl_down(s, o, 64);
    __shared__ float red[4];
    if ((threadIdx.x & 63) == 0) red[threadIdx.x >> 6] = s;
    __syncthreads();
    if (threadIdx.x == 0)
        outp[b * Cc + c] = (red[0] + red[1] + red[2] + red[3]) * (1.0f / N4);
}

// ci1[b][o] = bias[o] + sum_i w[o][i]*tmean[b][i]   (grid B, 64 threads)
__global__ __launch_bounds__(64) void ci1_kernel(
    const float* __restrict__ tmean, const bf16* __restrict__ wt,
    const bf16* __restrict__ bias, float* __restrict__ ci1v)
{
    const int b = blockIdx.x, o = threadIdx.x;
    float s = (float)bias[o];
    for (int i = 0; i < 64; i++) s += (float)wt[o * 64 + i] * tmean[b * 64 + i];
    ci1v[b * 64 + o] = s;
}

// g = t * ci1[b][c6] * u3   (elementwise over B*64*4096)
__global__ __launch_bounds__(256) void g_eltwise_kernel(
    const bf16* __restrict__ t, const float* __restrict__ ci1v,
    const bf16* __restrict__ u3, bf16* __restrict__ g)
{
    long idx = (long)blockIdx.x * 256 + threadIdx.x;
    long bc = idx >> 12;  // b*64 + c6
    g[idx] = (bf16)((float)t[idx] * ci1v[bc] * (float)u3[idx]);
}

// g2[b][cc][n] = gelu_exact(dd[b][cc][n]) * dd[b][cc+96][n], cc<96
__global__ __launch_bounds__(256) void gelu_mul_kernel(
    const bf16* __restrict__ dd, bf16* __restrict__ g2)
{
    long idx = (long)blockIdx.x * 256 + threadIdx.x;  // over B*96*4096
    int n = idx & 4095;
    long bc = idx >> 12;              // b*96 + cc
    long b = bc / 96, cc = bc - b * 96;
    float x1 = (float)dd[((b * 192 + cc) << 12) + n];
    float x2 = (float)dd[((b * 192 + cc + 96) << 12) + n];
    float g = 0.5f * x1 * (1.0f + erff(x1 * 0.70710678118654752f));
    g2[idx] = (bf16)(g * x2);
}

// at = (at + cmap)*sigmoid(smap) + convx*sigmoid(cm[b][c])   (in-place on at)
__global__ __launch_bounds__(256) void final_mix_kernel(
    bf16* __restrict__ at, const bf16* __restrict__ cmap,
    const bf16* __restrict__ smap, const bf16* __restrict__ convx,
    const float* __restrict__ cm)
{
    long idx = (long)blockIdx.x * 256 + threadIdx.x;
    long bc = idx >> 12;  // b*384 + c
    float a = (float)at[idx] + (float)cmap[idx];
    float s = 1.0f / (1.0f + expf(-(float)smap[idx]));
    float g = 1.0f / (1.0f + expf(-cm[bc]));
    at[idx] = (bf16)(a * s + (float)convx[idx] * g);
}

// ---------------------------------------------------------------------------
extern "C" void kernel_launch(void* const* d_in, const int* in_sizes, int n_in,
                              void* d_out, int out_size, void* d_ws, size_t ws_size,
                              hipStream_t stream)
{
    const int B = 8, C = 384, N = N4, C6 = 64, C2 = 192, C4 = 96;

    char* wsp = (char*)d_ws;
    size_t off = 0;
    auto alloc = [&](size_t bytes) -> char* {
        char* p = wsp + off; off += (bytes + 255) & ~(size_t)255; return p;
    };

    int* FLAG = (int*)alloc(256);

    // canonical bf16 copies of all inputs (dtype-adaptive)
    bf16* canon[27];
    for (int i = 0; i < 27; i++)
        canon[i] = (bf16*)alloc((size_t)in_sizes[i] * 2);

    detect_kernel<<<1, 64, 0, stream>>>((const unsigned int*)d_in[0], FLAG);
    for (int i = 0; i < 27; i++) {
        long n = in_sizes[i];
        int blocks = (int)((n + 255) / 256);
        convert_kernel<<<blocks, 256, 0, stream>>>(d_in[i], canon[i], n, FLAG);
    }

    const bf16* x       = canon[0];
    const bf16* temp    = canon[1];
    const bf16* qkv_w   = canon[2];
    const bf16* proj_w  = canon[3];
    const bf16* proj_b  = canon[4];
    const bf16* dw1_w   = canon[5];
    const bf16* dw1_b   = canon[6];
    const bf16* dw2_w   = canon[7];
    const bf16* dw2_b   = canon[8];
    const bf16* cp_in_w = canon[9];
    const bf16* cp_in_b = canon[10];
    const bf16* ci1_w   = canon[11];
    const bf16* ci1_b   = canon[12];
    const bf16* ci2a_w  = canon[13];
    const bf16* ci2a_b  = canon[14];
    const bf16* ci2b_w  = canon[15];
    const bf16* ci2b_b  = canon[16];
    const bf16* ci2c_w  = canon[17];
    const bf16* ci2c_b  = canon[18];
    const bf16* cp_out_w= canon[19];
    const bf16* cp_out_b= canon[20];
    const bf16* sp_in_w = canon[21];
    const bf16* sp_in_b = canon[22];
    const bf16* sp_dw_w = canon[23];
    const bf16* sp_dw_b = canon[24];
    const bf16* sp_out_w= canon[25];
    const bf16* sp_out_b= canon[26];

    bf16*  QKV   = (bf16*) alloc((size_t)B * 3 * C * N * 2);
    bf16*  AT    = (bf16*) alloc((size_t)B * C * N * 2);
    bf16*  CONV1 = (bf16*) alloc((size_t)B * C * N * 2);
    bf16*  CONVX = (bf16*) alloc((size_t)B * C * N * 2);
    bf16*  CMAP  = (bf16*) alloc((size_t)B * C * N * 2);
    bf16*  T     = (bf16*) alloc((size_t)B * C6 * N * 2);
    bf16*  U1    = (bf16*) alloc((size_t)B * C6 * N * 2);
    bf16*  U2    = (bf16*) alloc((size_t)B * C6 * N * 2);
    bf16*  SP    = (bf16*) alloc((size_t)B * C2 * N * 2);
    bf16*  DDb   = (bf16*) alloc((size_t)B * C2 * N * 2);
    float* PART  = (float*)alloc((size_t)64 * 32 * 2304 * 4);
    float* ATTN  = (float*)alloc((size_t)64 * 2304 * 4);
    float* INVN  = (float*)alloc((size_t)B * 768 * 4);
    float* TMEAN = (float*)alloc((size_t)B * 64 * 4);
    float* CI1V  = (float*)alloc((size_t)B * 64 * 4);
    float* CMv   = (float*)alloc((size_t)B * C * 4);
    // aliases over dead buffers
    bf16* SMAP = CONV1;   // conv1 dead after dw2
    bf16* G2   = SP;      // sp dead after sp_dw
    bf16* U3   = U1;      // u1 dead after ci2b
    bf16* G    = U2;      // u2 dead after ci2c

    // 1. QKV = qkv_w @ x  (per-batch)   -> (B, 3C, N), q|k|v channel blocks
    gemm_bf16_kernel<<<dim3(64, 18, 8), 256, 0, stream>>>(
        qkv_w, x, nullptr, QKV, 384, (long)C * N, (long)3 * C * N, nullptr);
    // 2. inverse L2 norms of q,k rows
    rownorm_kernel<<<dim3(768, 8), 256, 0, stream>>>(QKV, INVN);
    // 3. attention logits partials (MFMA, direct-from-global fragments)
    attn_logits_kernel<<<dim3(8, 64), 256, 0, stream>>>(QKV, PART);
    // 4. reduce + scale + softmax
    attn_softmax_kernel<<<64, 256, 0, stream>>>(PART, INVN, temp, ATTN);
    // 5. at = attn @ v
    attn_apply_kernel<<<dim3(16, 64), 256, 0, stream>>>(ATTN, QKV, AT);
    // 6. conv1 = dw1 (1x1) on v
    gemm_bf16_kernel<<<dim3(64, 6, 8), 256, 0, stream>>>(
        dw1_w, QKV + (size_t)2 * C * N, dw1_b, CONV1, 384, (long)3 * C * N, (long)C * N, nullptr);
    // 7. conv_x = depthwise 3x3 on conv1
    dw_kernel<<<dim3(16, 384, 8), 256, 0, stream>>>(CONV1, dw2_w, dw2_b, CONVX, 3, 1, 1);
    // 8. t = cp_in (1x1) on attened
    gemm_bf16_kernel<<<dim3(64, 1, 8), 256, 0, stream>>>(
        cp_in_w, AT, cp_in_b, T, 384, (long)C * N, (long)C6 * N, nullptr);
    // 9-10. ci1 = ci1_w @ mean(t)
    mean_kernel<<<dim3(64, 8), 256, 0, stream>>>(T, TMEAN);
    ci1_kernel<<<8, 64, 0, stream>>>(TMEAN, ci1_w, ci1_b, CI1V);
    // 11-13. ci2 chain: dw3x3, dw7x7 dil3, 1x1
    dw_kernel<<<dim3(16, 64, 8), 256, 0, stream>>>(T, ci2a_w, ci2a_b, U1, 3, 1, 1);
    dw_kernel<<<dim3(16, 64, 8), 256, 0, stream>>>(U1, ci2b_w, ci2b_b, U2, 7, 3, 9);
    gemm_bf16_kernel<<<dim3(64, 1, 8), 256, 0, stream>>>(
        ci2c_w, U2, ci2c_b, U3, 64, (long)C6 * N, (long)C6 * N, nullptr);
    // 14. g = t * ci1 * ci2
    g_eltwise_kernel<<<8192, 256, 0, stream>>>(T, CI1V, U3, G);
    // 15. channel_map = cp_out @ g
    gemm_bf16_kernel<<<dim3(64, 6, 8), 256, 0, stream>>>(
        cp_out_w, G, cp_out_b, CMAP, 64, (long)C6 * N, (long)C * N, nullptr);
    // 16. cm = mean(channel_map)
    mean_kernel<<<dim3(384, 8), 256, 0, stream>>>(CMAP, CMv);
    // 17. sp = sp_in @ conv_x
    gemm_bf16_kernel<<<dim3(64, 3, 8), 256, 0, stream>>>(
        sp_in_w, CONVX, sp_in_b, SP, 384, (long)C * N, (long)C2 * N, nullptr);
    // 18. d = depthwise 3x3 on sp
    dw_kernel<<<dim3(16, 192, 8), 256, 0, stream>>>(SP, sp_dw_w, sp_dw_b, DDb, 3, 1, 1);
    // 19. g2 = gelu(x1)*x2
    gelu_mul_kernel<<<12288, 256, 0, stream>>>(DDb, G2);
    // 20. spatial_map = sp_out @ g2
    gemm_bf16_kernel<<<dim3(64, 6, 8), 256, 0, stream>>>(
        sp_out_w, G2, sp_out_b, SMAP, 96, (long)C4 * N, (long)C * N, nullptr);
    // 21. at = (at + cmap)*sigmoid(smap) + convx*sigmoid(cm)
    final_mix_kernel<<<49152, 256, 0, stream>>>(AT, CMAP, SMAP, CONVX, CMv);
    // 22. out = proj_w @ at + proj_b  (dtype-adaptive output write)
    gemm_bf16_kernel<<<dim3(64, 6, 8), 256, 0, stream>>>(
        proj_w, AT, proj_b, d_out, 384, (long)C * N, (long)C * N, FLAG);
}

// Round 3
// 652.014 us; speedup vs baseline: 1.2031x; 1.2031x over previous
//
#include <hip/hip_runtime.h>
#include <hip/hip_bf16.h>

typedef __bf16 bf16;
typedef __bf16 bf16x8 __attribute__((ext_vector_type(8)));
typedef float f32x4 __attribute__((ext_vector_type(4)));

#define N4 4096
#define CCH 384

// ---------------------------------------------------------------------------
// Input dtype detection: 1 = inputs are bf16, 0 = inputs are f32.
// ---------------------------------------------------------------------------
__global__ void detect_kernel(const unsigned int* __restrict__ w, int* flag)
{
    if (threadIdx.x == 0 && blockIdx.x == 0) {
        int cnt = 0;
        for (int i = 0; i < 256; i++) {
            unsigned v = w[i];
            int elo = (v >> 7) & 0xFF, ehi = (v >> 23) & 0xFF;
            bool lo_ok = (elo >= 100 && elo <= 140) || ((v & 0xFFFFu) == 0);
            bool hi_ok = (ehi >= 100 && ehi <= 140) || ((v >> 16) == 0);
            if (lo_ok && hi_ok) cnt++;
        }
        *flag = (cnt >= 200) ? 1 : 0;
    }
}

// ---------------------------------------------------------------------------
// Fused canonicalization of ALL inputs to bf16 in one dispatch.
// ---------------------------------------------------------------------------
struct ConvArgs {
    const void* src[27];
    bf16* dst[27];
    long prefix[28];
};

__global__ __launch_bounds__(256) void convert_all_kernel(
    ConvArgs a, long total, const int* __restrict__ flag)
{
    long i = (long)blockIdx.x * 256 + threadIdx.x;
    if (i >= total) return;
    int lo = 0, hi = 26;
    while (lo < hi) { int mid = (lo + hi) >> 1; if (i >= a.prefix[mid + 1]) lo = mid + 1; else hi = mid; }
    long off = i - a.prefix[lo];
    if (*flag) a.dst[lo][off] = ((const bf16*)a.src[lo])[off];
    else       a.dst[lo][off] = (bf16)((const float*)a.src[lo])[off];
}

// ---------------------------------------------------------------------------
// 64x64-tile bf16 MFMA GEMM (for M in {64,192}): out[b][m][n] = W@X (+bias)
// ---------------------------------------------------------------------------
__global__ __launch_bounds__(256) void gemm_bf16_kernel(
    const bf16* __restrict__ Wg, const bf16* __restrict__ Xg,
    const bf16* __restrict__ bias, void* __restrict__ Og,
    int K, long xStride, long oStride, const int* __restrict__ outFlag)
{
    constexpr int LDP = 40;
    __shared__ bf16 Wt[64 * LDP];
    __shared__ bf16 Xt[64 * LDP];
    const int t = threadIdx.x;
    const int b = blockIdx.z;
    const int mBase = blockIdx.y << 6;
    const int nBase = blockIdx.x << 6;
    const bf16* Xb = Xg + (long)b * xStride;
    const int lane = t & 63, wv = t >> 6;
    const int wm = (wv >> 1) << 5, wn = (wv & 1) << 5;
    const int lr = lane & 15, qd = lane >> 4;
    const int wlm = t >> 2, wlk = (t & 3) << 3;
    const int xln = t & 63, xlk = (t >> 6) << 3;

    f32x4 acc[2][2] = {};

    for (int k0 = 0; k0 < K; k0 += 32) {
        bf16x8 wvv = *(const bf16x8*)(Wg + (long)(mBase + wlm) * K + k0 + wlk);
        const bf16* xp = Xb + (long)(k0 + xlk) * N4 + nBase + xln;
        bf16x8 xvv;
        #pragma unroll
        for (int j = 0; j < 8; j++) xvv[j] = xp[(long)j * N4];

        __syncthreads();
        *(bf16x8*)(&Wt[wlm * LDP + wlk]) = wvv;
        *(bf16x8*)(&Xt[xln * LDP + xlk]) = xvv;
        __syncthreads();

        bf16x8 af[2], bfr[2];
        #pragma unroll
        for (int i = 0; i < 2; i++) {
            af[i]  = *(const bf16x8*)(&Wt[(wm + i * 16 + lr) * LDP + qd * 8]);
            bfr[i] = *(const bf16x8*)(&Xt[(wn + i * 16 + lr) * LDP + qd * 8]);
        }
        #pragma unroll
        for (int i = 0; i < 2; i++)
            #pragma unroll
            for (int j = 0; j < 2; j++)
                acc[i][j] = __builtin_amdgcn_mfma_f32_16x16x32_bf16(
                    af[i], bfr[j], acc[i][j], 0, 0, 0);
    }

    const bool f32o = outFlag ? (*outFlag == 0) : false;
    #pragma unroll
    for (int i = 0; i < 2; i++)
        #pragma unroll
        for (int j = 0; j < 2; j++)
            #pragma unroll
            for (int r = 0; r < 4; r++) {
                int row = mBase + wm + i * 16 + qd * 4 + r;
                int col = nBase + wn + j * 16 + lr;
                float v = acc[i][j][r];
                if (bias) v += (float)bias[row];
                long oi = (long)b * oStride + (long)row * N4 + col;
                if (f32o) ((float*)Og)[oi] = v;
                else      ((bf16*)Og)[oi] = (bf16)v;
            }
}

// ---------------------------------------------------------------------------
// 128x128-tile bf16 MFMA GEMM (M%128==0). 4 waves, each 64x64 via 4x4 MFMA.
// ---------------------------------------------------------------------------
__global__ __launch_bounds__(256) void gemm128_kernel(
    const bf16* __restrict__ Wg, const bf16* __restrict__ Xg,
    const bf16* __restrict__ bias, void* __restrict__ Og,
    int K, long xStride, long oStride, const int* __restrict__ outFlag)
{
    constexpr int LDP = 40;
    __shared__ bf16 Wt[128 * LDP];
    __shared__ bf16 Xt[128 * LDP];
    const int t = threadIdx.x;
    const int b = blockIdx.z;
    const int mBase = blockIdx.y << 7;
    const int nBase = blockIdx.x << 7;
    const bf16* Xb = Xg + (long)b * xStride;
    const int lane = t & 63, wv = t >> 6;
    const int wm = (wv >> 1) << 6, wn = (wv & 1) << 6;
    const int lr = lane & 15, qd = lane >> 4;
    const int wrow0 = t >> 2, wk = (t & 3) << 3;     // W tile: 128 rows x 32 k

    f32x4 acc[4][4] = {};

    for (int k0 = 0; k0 < K; k0 += 32) {
        bf16x8 wv0 = *(const bf16x8*)(Wg + (long)(mBase + wrow0) * K + k0 + wk);
        bf16x8 wv1 = *(const bf16x8*)(Wg + (long)(mBase + wrow0 + 64) * K + k0 + wk);
        bf16x8 xv[2];
        #pragma unroll
        for (int g = 0; g < 2; g++) {
            int slot = g * 256 + t;
            int kg = slot >> 7, nn = slot & 127;
            const bf16* xp = Xb + (long)(k0 + kg * 8) * N4 + nBase + nn;
            #pragma unroll
            for (int j = 0; j < 8; j++) xv[g][j] = xp[(long)j * N4];
        }
        __syncthreads();
        *(bf16x8*)(&Wt[wrow0 * LDP + wk]) = wv0;
        *(bf16x8*)(&Wt[(wrow0 + 64) * LDP + wk]) = wv1;
        #pragma unroll
        for (int g = 0; g < 2; g++) {
            int slot = g * 256 + t;
            int kg = slot >> 7, nn = slot & 127;
            *(bf16x8*)(&Xt[nn * LDP + kg * 8]) = xv[g];
        }
        __syncthreads();

        bf16x8 af[4], bfr[4];
        #pragma unroll
        for (int i = 0; i < 4; i++) {
            af[i]  = *(const bf16x8*)(&Wt[(wm + i * 16 + lr) * LDP + qd * 8]);
            bfr[i] = *(const bf16x8*)(&Xt[(wn + i * 16 + lr) * LDP + qd * 8]);
        }
        #pragma unroll
        for (int i = 0; i < 4; i++)
            #pragma unroll
            for (int j = 0; j < 4; j++)
                acc[i][j] = __builtin_amdgcn_mfma_f32_16x16x32_bf16(
                    af[i], bfr[j], acc[i][j], 0, 0, 0);
    }

    const bool f32o = outFlag ? (*outFlag == 0) : false;
    #pragma unroll
    for (int i = 0; i < 4; i++)
        #pragma unroll
        for (int j = 0; j < 4; j++)
            #pragma unroll
            for (int r = 0; r < 4; r++) {
                int row = mBase + wm + i * 16 + qd * 4 + r;
                int col = nBase + wn + j * 16 + lr;
                float v = acc[i][j][r];
                if (bias) v += (float)bias[row];
                long oi = (long)b * oStride + (long)row * N4 + col;
                if (f32o) ((float*)Og)[oi] = v;
                else      ((bf16*)Og)[oi] = (bf16)v;
            }
}

// ---------------------------------------------------------------------------
// Row inverse L2 norms for q,k channels
// ---------------------------------------------------------------------------
__global__ __launch_bounds__(256) void rownorm_kernel(
    const bf16* __restrict__ qkv, float* __restrict__ invn)
{
    const int c = blockIdx.x, b = blockIdx.y;
    const bf16* p = qkv + (long)b * 3 * CCH * N4 + (long)c * N4;
    float s = 0.f;
    for (int i = threadIdx.x; i < N4; i += 256) { float v = (float)p[i]; s += v * v; }
    #pragma unroll
    for (int o = 32; o; o >>= 1) s += __shfl_down(s, o, 64);
    __shared__ float red[4];
    if ((threadIdx.x & 63) == 0) red[threadIdx.x >> 6] = s;
    __syncthreads();
    if (threadIdx.x == 0) {
        float tot = red[0] + red[1] + red[2] + red[3];
        invn[b * 768 + c] = 1.0f / fmaxf(sqrtf(tot), 1e-12f);
    }
}

// ---------------------------------------------------------------------------
// Attention logits partials (MFMA, direct-from-global fragments)
// ---------------------------------------------------------------------------
__global__ __launch_bounds__(256) void attn_logits_kernel(
    const bf16* __restrict__ qkv, float* __restrict__ part)
{
    const int kc = blockIdx.x;
    const int bh = blockIdx.y;
    const int b = bh >> 3, h = bh & 7;
    const int t = threadIdx.x, lane = t & 63, wv = t >> 6;
    const int lr = lane & 15, qd = lane >> 4;
    const bf16* qb = qkv + (long)b * 3 * CCH * N4 + (long)h * 48 * N4;
    const bf16* kb = qb + (long)CCH * N4;
    const int k0b = (kc * 4 + wv) * 128;
    f32x4 acc[3][3] = {};
    for (int s = 0; s < 4; s++) {
        const int k0 = k0b + s * 32;
        bf16x8 a[3], bb[3];
        #pragma unroll
        for (int i = 0; i < 3; i++) {
            a[i]  = *(const bf16x8*)(qb + (long)(i * 16 + lr) * N4 + k0 + qd * 8);
            bb[i] = *(const bf16x8*)(kb + (long)(i * 16 + lr) * N4 + k0 + qd * 8);
        }
        #pragma unroll
        for (int i = 0; i < 3; i++)
            #pragma unroll
            for (int j = 0; j < 3; j++)
                acc[i][j] = __builtin_amdgcn_mfma_f32_16x16x32_bf16(
                    a[i], bb[j], acc[i][j], 0, 0, 0);
    }
    float* pp = part + ((long)bh * 32 + kc * 4 + wv) * 2304;
    #pragma unroll
    for (int i = 0; i < 3; i++)
        #pragma unroll
        for (int j = 0; j < 3; j++)
            #pragma unroll
            for (int r = 0; r < 4; r++)
                pp[(i * 16 + qd * 4 + r) * 48 + j * 16 + lr] = acc[i][j][r];
}

// ---------------------------------------------------------------------------
// Sum partials, scale, softmax
// ---------------------------------------------------------------------------
__global__ __launch_bounds__(256) void attn_softmax_kernel(
    const float* __restrict__ part, const float* __restrict__ invn,
    const bf16* __restrict__ temp, float* __restrict__ attn)
{
    __shared__ float sl[2304];
    const int bh = blockIdx.x, b = bh >> 3, h = bh & 7;
    const int t = threadIdx.x;
    const float tmp = (float)temp[h];
    for (int idx = t; idx < 2304; idx += 256) {
        float s = 0.f;
        for (int p = 0; p < 32; p++) s += part[((long)bh * 32 + p) * 2304 + idx];
        int d = idx / 48, e = idx - d * 48;
        s *= invn[b * 768 + h * 48 + d] * invn[b * 768 + 384 + h * 48 + e] * tmp;
        sl[idx] = s;
    }
    __syncthreads();
    if (t < 48) {
        float m = -1e30f;
        #pragma unroll
        for (int e = 0; e < 48; e++) m = fmaxf(m, sl[t * 48 + e]);
        float ex[48]; float sum = 0.f;
        #pragma unroll
        for (int e = 0; e < 48; e++) { ex[e] = expf(sl[t * 48 + e] - m); sum += ex[e]; }
        float inv = 1.0f / sum;
        #pragma unroll
        for (int e = 0; e < 48; e++) attn[(long)bh * 2304 + t * 48 + e] = ex[e] * inv;
    }
}

// ---------------------------------------------------------------------------
// at = attn @ v
// ---------------------------------------------------------------------------
__global__ __launch_bounds__(256) void attn_apply_kernel(
    const float* __restrict__ attn, const bf16* __restrict__ qkv,
    bf16* __restrict__ at)
{
    __shared__ float sa[2304];
    const int bh = blockIdx.y, b = bh >> 3, h = bh & 7;
    const int t = threadIdx.x;
    for (int i = t; i < 2304; i += 256) sa[i] = attn[(long)bh * 2304 + i];
    __syncthreads();
    const int n = blockIdx.x * 256 + t;
    const bf16* vb = qkv + (long)b * 3 * CCH * N4 + (long)(2 * CCH + h * 48) * N4;
    float acc[48];
    #pragma unroll
    for (int d = 0; d < 48; d++) acc[d] = 0.f;
    for (int e = 0; e < 48; e++) {
        float vv = (float)vb[(long)e * N4 + n];
        #pragma unroll
        for (int d = 0; d < 48; d++) acc[d] += sa[d * 48 + e] * vv;
    }
    bf16* ab = at + (long)b * CCH * N4 + (long)h * 48 * N4 + n;
    #pragma unroll
    for (int d = 0; d < 48; d++) ab[(long)d * N4] = (bf16)acc[d];
}

// ---------------------------------------------------------------------------
// Templated depthwise conv: 8 outputs/thread, vector loads, full unroll.
// Block 512 threads = one (b,c) plane (64 rows x 8 chunks). grid = B*CH.
// ---------------------------------------------------------------------------
template<int S, int DIL, int PAD, int CH>
__global__ __launch_bounds__(512) void dw_conv_kernel(
    const bf16* __restrict__ in, const bf16* __restrict__ wt,
    const bf16* __restrict__ bias, bf16* __restrict__ outp)
{
    constexpr int SPAN = 8 + (S - 1) * DIL;
    constexpr int CL = (PAD + 7) / 8;
    constexpr int CR = ((S - 1) * DIL - PAD + 7) / 8;
    constexpr int NC = CL + 1 + CR;
    const int p = blockIdx.x;                 // plane = b*CH + c
    const int c = p % CH;
    const int u = threadIdx.x;
    const int y = u >> 3, x0 = (u & 7) << 3;
    const bf16* ip = in + (long)p * N4;

    float wf[S * S];
    #pragma unroll
    for (int i = 0; i < S * S; i++) wf[i] = (float)wt[c * S * S + i];

    float acc[8];
    float bz = (float)bias[c];
    #pragma unroll
    for (int px = 0; px < 8; px++) acc[px] = bz;

    #pragma unroll
    for (int i = 0; i < S; i++) {
        int yy = y + i * DIL - PAD;
        if (yy >= 0 && yy < 64) {
            const bf16* rp = ip + yy * 64;
            bf16 chunk[NC][8];
            #pragma unroll
            for (int cix = 0; cix < NC; cix++) {
                int xx = x0 + (cix - CL) * 8;      // aligned: fully in or out
                if (xx >= 0 && xx < 64) {
                    *(bf16x8*)chunk[cix] = *(const bf16x8*)(rp + xx);
                } else {
                    #pragma unroll
                    for (int e = 0; e < 8; e++) chunk[cix][e] = (bf16)0.f;
                }
            }
            float w[SPAN];
            #pragma unroll
            for (int pp = 0; pp < SPAN; pp++) {
                constexpr int BASE = CL * 8 - PAD;
                int o = pp + BASE;
                w[pp] = (float)chunk[o >> 3][o & 7];
            }
            #pragma unroll
            for (int j = 0; j < S; j++) {
                float wj = wf[i * S + j];
                #pragma unroll
                for (int px = 0; px < 8; px++)
                    acc[px] += wj * w[px + j * DIL];
            }
        }
    }
    bf16x8 ov;
    #pragma unroll
    for (int px = 0; px < 8; px++) ov[px] = (bf16)acc[px];
    *(bf16x8*)(outp + (long)p * N4 + y * 64 + x0) = ov;
}

// mean over spatial: out[b*C + c], grid (C, B)
__global__ __launch_bounds__(256) void mean_kernel(
    const bf16* __restrict__ in, float* __restrict__ outp)
{
    const int Cc = gridDim.x;
    const int c = blockIdx.x, b = blockIdx.y;
    const bf16* p = in + ((long)b * Cc + c) * N4;
    float s = 0.f;
    for (int i = threadIdx.x; i < N4; i += 256) s += (float)p[i];
    #pragma unroll
    for (int o = 32; o; o >>= 1) s += __shfl_down(s, o, 64);
    __shared__ float red[4];
    if ((threadIdx.x & 63) == 0) red[threadIdx.x >> 6] = s;
    __syncthreads();
    if (threadIdx.x == 0)
        outp[b * Cc + c] = (red[0] + red[1] + red[2] + red[3]) * (1.0f / N4);
}

__global__ __launch_bounds__(64) void ci1_kernel(
    const float* __restrict__ tmean, const bf16* __restrict__ wt,
    const bf16* __restrict__ bias, float* __restrict__ ci1v)
{
    const int b = blockIdx.x, o = threadIdx.x;
    float s = (float)bias[o];
    for (int i = 0; i < 64; i++) s += (float)wt[o * 64 + i] * tmean[b * 64 + i];
    ci1v[b * 64 + o] = s;
}

__global__ __launch_bounds__(256) void g_eltwise_kernel(
    const bf16* __restrict__ t, const float* __restrict__ ci1v,
    const bf16* __restrict__ u3, bf16* __restrict__ g)
{
    long idx = (long)blockIdx.x * 256 + threadIdx.x;
    long bc = idx >> 12;
    g[idx] = (bf16)((float)t[idx] * ci1v[bc] * (float)u3[idx]);
}

__global__ __launch_bounds__(256) void gelu_mul_kernel(
    const bf16* __restrict__ dd, bf16* __restrict__ g2)
{
    long idx = (long)blockIdx.x * 256 + threadIdx.x;
    int n = idx & 4095;
    long bc = idx >> 12;
    long b = bc / 96, cc = bc - b * 96;
    float x1 = (float)dd[((b * 192 + cc) << 12) + n];
    float x2 = (float)dd[((b * 192 + cc + 96) << 12) + n];
    float g = 0.5f * x1 * (1.0f + erff(x1 * 0.70710678118654752f));
    g2[idx] = (bf16)(g * x2);
}

__global__ __launch_bounds__(256) void final_mix_kernel(
    bf16* __restrict__ at, const bf16* __restrict__ cmap,
    const bf16* __restrict__ smap, const bf16* __restrict__ convx,
    const float* __restrict__ cm)
{
    long idx = (long)blockIdx.x * 256 + threadIdx.x;
    long bc = idx >> 12;
    float a = (float)at[idx] + (float)cmap[idx];
    float s = 1.0f / (1.0f + expf(-(float)smap[idx]));
    float g = 1.0f / (1.0f + expf(-cm[bc]));
    at[idx] = (bf16)(a * s + (float)convx[idx] * g);
}

// ---------------------------------------------------------------------------
extern "C" void kernel_launch(void* const* d_in, const int* in_sizes, int n_in,
                              void* d_out, int out_size, void* d_ws, size_t ws_size,
                              hipStream_t stream)
{
    const int B = 8, C = 384, N = N4, C6 = 64, C2 = 192, C4 = 96;

    char* wsp = (char*)d_ws;
    size_t off = 0;
    auto alloc = [&](size_t bytes) -> char* {
        char* p = wsp + off; off += (bytes + 255) & ~(size_t)255; return p;
    };

    int* FLAG = (int*)alloc(256);

    bf16* canon[27];
    ConvArgs ca;
    long pre = 0;
    for (int i = 0; i < 27; i++) {
        canon[i] = (bf16*)alloc((size_t)in_sizes[i] * 2);
        ca.src[i] = d_in[i];
        ca.dst[i] = canon[i];
        ca.prefix[i] = pre;
        pre += in_sizes[i];
    }
    ca.prefix[27] = pre;

    detect_kernel<<<1, 64, 0, stream>>>((const unsigned int*)d_in[0], FLAG);
    convert_all_kernel<<<(int)((pre + 255) / 256), 256, 0, stream>>>(ca, pre, FLAG);

    const bf16* x       = canon[0];
    const bf16* temp    = canon[1];
    const bf16* qkv_w   = canon[2];
    const bf16* proj_w  = canon[3];
    const bf16* proj_b  = canon[4];
    const bf16* dw1_w   = canon[5];
    const bf16* dw1_b   = canon[6];
    const bf16* dw2_w   = canon[7];
    const bf16* dw2_b   = canon[8];
    const bf16* cp_in_w = canon[9];
    const bf16* cp_in_b = canon[10];
    const bf16* ci1_w   = canon[11];
    const bf16* ci1_b   = canon[12];
    const bf16* ci2a_w  = canon[13];
    const bf16* ci2a_b  = canon[14];
    const bf16* ci2b_w  = canon[15];
    const bf16* ci2b_b  = canon[16];
    const bf16* ci2c_w  = canon[17];
    const bf16* ci2c_b  = canon[18];
    const bf16* cp_out_w= canon[19];
    const bf16* cp_out_b= canon[20];
    const bf16* sp_in_w = canon[21];
    const bf16* sp_in_b = canon[22];
    const bf16* sp_dw_w = canon[23];
    const bf16* sp_dw_b = canon[24];
    const bf16* sp_out_w= canon[25];
    const bf16* sp_out_b= canon[26];

    bf16*  QKV   = (bf16*) alloc((size_t)B * 3 * C * N * 2);
    bf16*  AT    = (bf16*) alloc((size_t)B * C * N * 2);
    bf16*  CONV1 = (bf16*) alloc((size_t)B * C * N * 2);
    bf16*  CONVX = (bf16*) alloc((size_t)B * C * N * 2);
    bf16*  CMAP  = (bf16*) alloc((size_t)B * C * N * 2);
    bf16*  T     = (bf16*) alloc((size_t)B * C6 * N * 2);
    bf16*  U1    = (bf16*) alloc((size_t)B * C6 * N * 2);
    bf16*  U2    = (bf16*) alloc((size_t)B * C6 * N * 2);
    bf16*  SP    = (bf16*) alloc((size_t)B * C2 * N * 2);
    bf16*  DDb   = (bf16*) alloc((size_t)B * C2 * N * 2);
    float* PART  = (float*)alloc((size_t)64 * 32 * 2304 * 4);
    float* ATTN  = (float*)alloc((size_t)64 * 2304 * 4);
    float* INVN  = (float*)alloc((size_t)B * 768 * 4);
    float* TMEAN = (float*)alloc((size_t)B * 64 * 4);
    float* CI1V  = (float*)alloc((size_t)B * 64 * 4);
    float* CMv   = (float*)alloc((size_t)B * C * 4);
    bf16* SMAP = CONV1;   // conv1 dead after dw2
    bf16* G2   = SP;      // sp dead after sp_dw
    bf16* U3   = U1;      // u1 dead after ci2b
    bf16* G    = U2;      // u2 dead after ci2c

    // 1. QKV = qkv_w @ x
    gemm128_kernel<<<dim3(32, 9, 8), 256, 0, stream>>>(
        qkv_w, x, nullptr, QKV, 384, (long)C * N, (long)3 * C * N, nullptr);
    // 2. inverse L2 norms of q,k rows
    rownorm_kernel<<<dim3(768, 8), 256, 0, stream>>>(QKV, INVN);
    // 3-5. attention
    attn_logits_kernel<<<dim3(8, 64), 256, 0, stream>>>(QKV, PART);
    attn_softmax_kernel<<<64, 256, 0, stream>>>(PART, INVN, temp, ATTN);
    attn_apply_kernel<<<dim3(16, 64), 256, 0, stream>>>(ATTN, QKV, AT);
    // 6. conv1 = dw1 (1x1) on v
    gemm128_kernel<<<dim3(32, 3, 8), 256, 0, stream>>>(
        dw1_w, QKV + (size_t)2 * C * N, dw1_b, CONV1, 384, (long)3 * C * N, (long)C * N, nullptr);
    // 7. conv_x = depthwise 3x3
    dw_conv_kernel<3, 1, 1, 384><<<B * 384, 512, 0, stream>>>(CONV1, dw2_w, dw2_b, CONVX);
    // 8. t = cp_in (1x1) on attened
    gemm_bf16_kernel<<<dim3(64, 1, 8), 256, 0, stream>>>(
        cp_in_w, AT, cp_in_b, T, 384, (long)C * N, (long)C6 * N, nullptr);
    // 9-10. ci1
    mean_kernel<<<dim3(64, 8), 256, 0, stream>>>(T, TMEAN);
    ci1_kernel<<<8, 64, 0, stream>>>(TMEAN, ci1_w, ci1_b, CI1V);
    // 11-13. ci2 chain
    dw_conv_kernel<3, 1, 1, 64><<<B * 64, 512, 0, stream>>>(T, ci2a_w, ci2a_b, U1);
    dw_conv_kernel<7, 3, 9, 64><<<B * 64, 512, 0, stream>>>(U1, ci2b_w, ci2b_b, U2);
    gemm_bf16_kernel<<<dim3(64, 1, 8), 256, 0, stream>>>(
        ci2c_w, U2, ci2c_b, U3, 64, (long)C6 * N, (long)C6 * N, nullptr);
    // 14. g = t * ci1 * ci2
    g_eltwise_kernel<<<8192, 256, 0, stream>>>(T, CI1V, U3, G);
    // 15. channel_map = cp_out @ g
    gemm128_kernel<<<dim3(32, 3, 8), 256, 0, stream>>>(
        cp_out_w, G, cp_out_b, CMAP, 64, (long)C6 * N, (long)C * N, nullptr);
    // 16. cm
    mean_kernel<<<dim3(384, 8), 256, 0, stream>>>(CMAP, CMv);
    // 17. sp = sp_in @ conv_x
    gemm_bf16_kernel<<<dim3(64, 3, 8), 256, 0, stream>>>(
        sp_in_w, CONVX, sp_in_b, SP, 384, (long)C * N, (long)C2 * N, nullptr);
    // 18. d = depthwise 3x3 on sp
    dw_conv_kernel<3, 1, 1, 192><<<B * 192, 512, 0, stream>>>(SP, sp_dw_w, sp_dw_b, DDb);
    // 19. g2 = gelu(x1)*x2
    gelu_mul_kernel<<<12288, 256, 0, stream>>>(DDb, G2);
    // 20. spatial_map = sp_out @ g2
    gemm128_kernel<<<dim3(32, 3, 8), 256, 0, stream>>>(
        sp_out_w, G2, sp_out_b, SMAP, 96, (long)C4 * N, (long)C * N, nullptr);
    // 21. final mix
    final_mix_kernel<<<49152, 256, 0, stream>>>(AT, CMAP, SMAP, CONVX, CMv);
    // 22. out = proj_w @ at + proj_b
    gemm128_kernel<<<dim3(32, 3, 8), 256, 0, stream>>>(
        proj_w, AT, proj_b, d_out, 384, (long)C * N, (long)C * N, FLAG);
}

// Round 5
// 516.627 us; speedup vs baseline: 1.5184x; 1.2621x over previous
//
#include <hip/hip_runtime.h>
#include <hip/hip_bf16.h>

typedef __bf16 bf16;
typedef __bf16 bf16x8 __attribute__((ext_vector_type(8)));
typedef float f32x4 __attribute__((ext_vector_type(4)));

#define N4 4096
#define CCH 384

// ---------------------------------------------------------------------------
// Fused f32 -> bf16 conversion of the 9 MFMA-feeding tensors, 8 elems/thread.
// Inputs are f32 (measured: R1/R4 direct-bf16 cast -> NaN; R2/R3 convert with
// flag=0 -> pass. R3 FETCH_SIZE was L3-absorbed, not evidence of bf16.)
// ---------------------------------------------------------------------------
struct CvtArgs {
    const float* src[9];
    bf16* dst[9];
    long gpre[10];     // prefix sums in 8-element groups
};

__global__ __launch_bounds__(256) void cvt_kernel(CvtArgs a, long totalGroups)
{
    long g = (long)blockIdx.x * 256 + threadIdx.x;
    if (g >= totalGroups) return;
    int lo = 0, hi = 8;
    while (lo < hi) { int mid = (lo + hi) >> 1; if (g >= a.gpre[mid + 1]) lo = mid + 1; else hi = mid; }
    long off = (g - a.gpre[lo]) << 3;
    const float* s = a.src[lo] + off;
    float4 v0 = *(const float4*)s;
    float4 v1 = *(const float4*)(s + 4);
    bf16x8 o;
    o[0] = (bf16)v0.x; o[1] = (bf16)v0.y; o[2] = (bf16)v0.z; o[3] = (bf16)v0.w;
    o[4] = (bf16)v1.x; o[5] = (bf16)v1.y; o[6] = (bf16)v1.z; o[7] = (bf16)v1.w;
    *(bf16x8*)(a.dst[lo] + off) = o;
}

// ---------------------------------------------------------------------------
// 64x64-tile bf16 MFMA GEMM. 1D grid, XCD swizzle: blockIdx&7 = batch.
// bias is f32. f32out selects output dtype (proj writes f32 d_out).
// ---------------------------------------------------------------------------
__global__ __launch_bounds__(256) void gemm_bf16_kernel(
    const bf16* __restrict__ Wg, const bf16* __restrict__ Xg,
    const float* __restrict__ bias, void* __restrict__ Og,
    int K, long xStride, long oStride, int f32out)
{
    constexpr int LDP = 40;
    __shared__ bf16 Wt[64 * LDP];
    __shared__ bf16 Xt[64 * LDP];
    const int t = threadIdx.x;
    const int lin = blockIdx.x;
    const int b = lin & 7;
    const int rest = lin >> 3;
    const int nBase = (rest & 63) << 6;
    const int mBase = (rest >> 6) << 6;
    const bf16* Xb = Xg + (long)b * xStride;
    const int lane = t & 63, wv = t >> 6;
    const int wm = (wv >> 1) << 5, wn = (wv & 1) << 5;
    const int lr = lane & 15, qd = lane >> 4;
    const int wlm = t >> 2, wlk = (t & 3) << 3;
    const int xln = t & 63, xlk = (t >> 6) << 3;

    f32x4 acc[2][2] = {};

    for (int k0 = 0; k0 < K; k0 += 32) {
        bf16x8 wvv = *(const bf16x8*)(Wg + (long)(mBase + wlm) * K + k0 + wlk);
        const bf16* xp = Xb + (long)(k0 + xlk) * N4 + nBase + xln;
        bf16x8 xvv;
        #pragma unroll
        for (int j = 0; j < 8; j++) xvv[j] = xp[(long)j * N4];

        __syncthreads();
        *(bf16x8*)(&Wt[wlm * LDP + wlk]) = wvv;
        *(bf16x8*)(&Xt[xln * LDP + xlk]) = xvv;
        __syncthreads();

        bf16x8 af[2], bfr[2];
        #pragma unroll
        for (int i = 0; i < 2; i++) {
            af[i]  = *(const bf16x8*)(&Wt[(wm + i * 16 + lr) * LDP + qd * 8]);
            bfr[i] = *(const bf16x8*)(&Xt[(wn + i * 16 + lr) * LDP + qd * 8]);
        }
        #pragma unroll
        for (int i = 0; i < 2; i++)
            #pragma unroll
            for (int j = 0; j < 2; j++)
                acc[i][j] = __builtin_amdgcn_mfma_f32_16x16x32_bf16(
                    af[i], bfr[j], acc[i][j], 0, 0, 0);
    }

    #pragma unroll
    for (int i = 0; i < 2; i++)
        #pragma unroll
        for (int j = 0; j < 2; j++)
            #pragma unroll
            for (int r = 0; r < 4; r++) {
                int row = mBase + wm + i * 16 + qd * 4 + r;
                int col = nBase + wn + j * 16 + lr;
                float v = acc[i][j][r];
                if (bias) v += bias[row];
                long oi = (long)b * oStride + (long)row * N4 + col;
                if (f32out) ((float*)Og)[oi] = v;
                else        ((bf16*)Og)[oi] = (bf16)v;
            }
}

// ---------------------------------------------------------------------------
// 128x128-tile bf16 MFMA GEMM (M%128==0). 1D grid, XCD swizzle as above.
// ---------------------------------------------------------------------------
__global__ __launch_bounds__(256) void gemm128_kernel(
    const bf16* __restrict__ Wg, const bf16* __restrict__ Xg,
    const float* __restrict__ bias, void* __restrict__ Og,
    int K, long xStride, long oStride, int f32out)
{
    constexpr int LDP = 40;
    __shared__ bf16 Wt[128 * LDP];
    __shared__ bf16 Xt[128 * LDP];
    const int t = threadIdx.x;
    const int lin = blockIdx.x;
    const int b = lin & 7;
    const int rest = lin >> 3;
    const int nBase = (rest & 31) << 7;
    const int mBase = (rest >> 5) << 7;
    const bf16* Xb = Xg + (long)b * xStride;
    const int lane = t & 63, wv = t >> 6;
    const int wm = (wv >> 1) << 6, wn = (wv & 1) << 6;
    const int lr = lane & 15, qd = lane >> 4;
    const int wrow0 = t >> 2, wk = (t & 3) << 3;

    f32x4 acc[4][4] = {};

    for (int k0 = 0; k0 < K; k0 += 32) {
        bf16x8 wv0 = *(const bf16x8*)(Wg + (long)(mBase + wrow0) * K + k0 + wk);
        bf16x8 wv1 = *(const bf16x8*)(Wg + (long)(mBase + wrow0 + 64) * K + k0 + wk);
        bf16x8 xv[2];
        #pragma unroll
        for (int g = 0; g < 2; g++) {
            int slot = g * 256 + t;
            int kg = slot >> 7, nn = slot & 127;
            const bf16* xp = Xb + (long)(k0 + kg * 8) * N4 + nBase + nn;
            #pragma unroll
            for (int j = 0; j < 8; j++) xv[g][j] = xp[(long)j * N4];
        }
        __syncthreads();
        *(bf16x8*)(&Wt[wrow0 * LDP + wk]) = wv0;
        *(bf16x8*)(&Wt[(wrow0 + 64) * LDP + wk]) = wv1;
        #pragma unroll
        for (int g = 0; g < 2; g++) {
            int slot = g * 256 + t;
            int kg = slot >> 7, nn = slot & 127;
            *(bf16x8*)(&Xt[nn * LDP + kg * 8]) = xv[g];
        }
        __syncthreads();

        bf16x8 af[4], bfr[4];
        #pragma unroll
        for (int i = 0; i < 4; i++) {
            af[i]  = *(const bf16x8*)(&Wt[(wm + i * 16 + lr) * LDP + qd * 8]);
            bfr[i] = *(const bf16x8*)(&Xt[(wn + i * 16 + lr) * LDP + qd * 8]);
        }
        #pragma unroll
        for (int i = 0; i < 4; i++)
            #pragma unroll
            for (int j = 0; j < 4; j++)
                acc[i][j] = __builtin_amdgcn_mfma_f32_16x16x32_bf16(
                    af[i], bfr[j], acc[i][j], 0, 0, 0);
    }

    #pragma unroll
    for (int i = 0; i < 4; i++)
        #pragma unroll
        for (int j = 0; j < 4; j++)
            #pragma unroll
            for (int r = 0; r < 4; r++) {
                int row = mBase + wm + i * 16 + qd * 4 + r;
                int col = nBase + wn + j * 16 + lr;
                float v = acc[i][j][r];
                if (bias) v += bias[row];
                long oi = (long)b * oStride + (long)row * N4 + col;
                if (f32out) ((float*)Og)[oi] = v;
                else        ((bf16*)Og)[oi] = (bf16)v;
            }
}

// ---------------------------------------------------------------------------
// Row inverse L2 norms for q,k channels (bf16x8 vector loads)
// ---------------------------------------------------------------------------
__global__ __launch_bounds__(256) void rownorm_kernel(
    const bf16* __restrict__ qkv, float* __restrict__ invn)
{
    const int c = blockIdx.x, b = blockIdx.y;
    const bf16* p = qkv + (long)b * 3 * CCH * N4 + (long)c * N4;
    float s = 0.f;
    for (int i = threadIdx.x * 8; i < N4; i += 2048) {
        bf16x8 v = *(const bf16x8*)(p + i);
        #pragma unroll
        for (int e = 0; e < 8; e++) { float f = (float)v[e]; s += f * f; }
    }
    #pragma unroll
    for (int o = 32; o; o >>= 1) s += __shfl_down(s, o, 64);
    __shared__ float red[4];
    if ((threadIdx.x & 63) == 0) red[threadIdx.x >> 6] = s;
    __syncthreads();
    if (threadIdx.x == 0) {
        float tot = red[0] + red[1] + red[2] + red[3];
        invn[b * 768 + c] = 1.0f / fmaxf(sqrtf(tot), 1e-12f);
    }
}

// ---------------------------------------------------------------------------
// Attention logits partials (MFMA, direct-from-global fragments)
// ---------------------------------------------------------------------------
__global__ __launch_bounds__(256) void attn_logits_kernel(
    const bf16* __restrict__ qkv, float* __restrict__ part)
{
    const int kc = blockIdx.x;
    const int bh = blockIdx.y;
    const int b = bh >> 3, h = bh & 7;
    const int t = threadIdx.x, lane = t & 63, wv = t >> 6;
    const int lr = lane & 15, qd = lane >> 4;
    const bf16* qb = qkv + (long)b * 3 * CCH * N4 + (long)h * 48 * N4;
    const bf16* kb = qb + (long)CCH * N4;
    const int k0b = (kc * 4 + wv) * 128;
    f32x4 acc[3][3] = {};
    for (int s = 0; s < 4; s++) {
        const int k0 = k0b + s * 32;
        bf16x8 a[3], bb[3];
        #pragma unroll
        for (int i = 0; i < 3; i++) {
            a[i]  = *(const bf16x8*)(qb + (long)(i * 16 + lr) * N4 + k0 + qd * 8);
            bb[i] = *(const bf16x8*)(kb + (long)(i * 16 + lr) * N4 + k0 + qd * 8);
        }
        #pragma unroll
        for (int i = 0; i < 3; i++)
            #pragma unroll
            for (int j = 0; j < 3; j++)
                acc[i][j] = __builtin_amdgcn_mfma_f32_16x16x32_bf16(
                    a[i], bb[j], acc[i][j], 0, 0, 0);
    }
    float* pp = part + ((long)bh * 32 + kc * 4 + wv) * 2304;
    #pragma unroll
    for (int i = 0; i < 3; i++)
        #pragma unroll
        for (int j = 0; j < 3; j++)
            #pragma unroll
            for (int r = 0; r < 4; r++)
                pp[(i * 16 + qd * 4 + r) * 48 + j * 16 + lr] = acc[i][j][r];
}

// ---------------------------------------------------------------------------
// Sum partials, scale, softmax (temperature read as f32)
// ---------------------------------------------------------------------------
__global__ __launch_bounds__(256) void attn_softmax_kernel(
    const float* __restrict__ part, const float* __restrict__ invn,
    const float* __restrict__ temp, float* __restrict__ attn)
{
    __shared__ float sl[2304];
    const int bh = blockIdx.x, b = bh >> 3, h = bh & 7;
    const int t = threadIdx.x;
    const float tmp = temp[h];
    for (int idx = t; idx < 2304; idx += 256) {
        float s = 0.f;
        for (int p = 0; p < 32; p++) s += part[((long)bh * 32 + p) * 2304 + idx];
        int d = idx / 48, e = idx - d * 48;
        s *= invn[b * 768 + h * 48 + d] * invn[b * 768 + 384 + h * 48 + e] * tmp;
        sl[idx] = s;
    }
    __syncthreads();
    if (t < 48) {
        float m = -1e30f;
        #pragma unroll
        for (int e = 0; e < 48; e++) m = fmaxf(m, sl[t * 48 + e]);
        float ex[48]; float sum = 0.f;
        #pragma unroll
        for (int e = 0; e < 48; e++) { ex[e] = expf(sl[t * 48 + e] - m); sum += ex[e]; }
        float inv = 1.0f / sum;
        #pragma unroll
        for (int e = 0; e < 48; e++) attn[(long)bh * 2304 + t * 48 + e] = ex[e] * inv;
    }
}

// ---------------------------------------------------------------------------
// at = attn @ v
// ---------------------------------------------------------------------------
__global__ __launch_bounds__(256) void attn_apply_kernel(
    const float* __restrict__ attn, const bf16* __restrict__ qkv,
    bf16* __restrict__ at)
{
    __shared__ float sa[2304];
    const int bh = blockIdx.y, b = bh >> 3, h = bh & 7;
    const int t = threadIdx.x;
    for (int i = t; i < 2304; i += 256) sa[i] = attn[(long)bh * 2304 + i];
    __syncthreads();
    const int n = blockIdx.x * 256 + t;
    const bf16* vb = qkv + (long)b * 3 * CCH * N4 + (long)(2 * CCH + h * 48) * N4;
    float acc[48];
    #pragma unroll
    for (int d = 0; d < 48; d++) acc[d] = 0.f;
    for (int e = 0; e < 48; e++) {
        float vv = (float)vb[(long)e * N4 + n];
        #pragma unroll
        for (int d = 0; d < 48; d++) acc[d] += sa[d * 48 + e] * vv;
    }
    bf16* ab = at + (long)b * CCH * N4 + (long)h * 48 * N4 + n;
    #pragma unroll
    for (int d = 0; d < 48; d++) ab[(long)d * N4] = (bf16)acc[d];
}

// ---------------------------------------------------------------------------
// Templated depthwise conv: weights/bias read as f32 directly.
// ---------------------------------------------------------------------------
template<int S, int DIL, int PAD, int CH>
__global__ __launch_bounds__(512) void dw_conv_kernel(
    const bf16* __restrict__ in, const float* __restrict__ wt,
    const float* __restrict__ bias, bf16* __restrict__ outp)
{
    constexpr int SPAN = 8 + (S - 1) * DIL;
    constexpr int CL = (PAD + 7) / 8;
    constexpr int CR = ((S - 1) * DIL - PAD + 7) / 8;
    constexpr int NC = CL + 1 + CR;
    const int p = blockIdx.x;
    const int c = p % CH;
    const int u = threadIdx.x;
    const int y = u >> 3, x0 = (u & 7) << 3;
    const bf16* ip = in + (long)p * N4;

    float wf[S * S];
    #pragma unroll
    for (int i = 0; i < S * S; i++) wf[i] = wt[c * S * S + i];

    float acc[8];
    float bz = bias[c];
    #pragma unroll
    for (int px = 0; px < 8; px++) acc[px] = bz;

    #pragma unroll
    for (int i = 0; i < S; i++) {
        int yy = y + i * DIL - PAD;
        if (yy >= 0 && yy < 64) {
            const bf16* rp = ip + yy * 64;
            bf16 chunk[NC][8];
            #pragma unroll
            for (int cix = 0; cix < NC; cix++) {
                int xx = x0 + (cix - CL) * 8;
                if (xx >= 0 && xx < 64) {
                    *(bf16x8*)chunk[cix] = *(const bf16x8*)(rp + xx);
                } else {
                    #pragma unroll
                    for (int e = 0; e < 8; e++) chunk[cix][e] = (bf16)0.f;
                }
            }
            float w[SPAN];
            #pragma unroll
            for (int pp = 0; pp < SPAN; pp++) {
                constexpr int BASE = CL * 8 - PAD;
                int o = pp + BASE;
                w[pp] = (float)chunk[o >> 3][o & 7];
            }
            #pragma unroll
            for (int j = 0; j < S; j++) {
                float wj = wf[i * S + j];
                #pragma unroll
                for (int px = 0; px < 8; px++)
                    acc[px] += wj * w[px + j * DIL];
            }
        }
    }
    bf16x8 ov;
    #pragma unroll
    for (int px = 0; px < 8; px++) ov[px] = (bf16)acc[px];
    *(bf16x8*)(outp + (long)p * N4 + y * 64 + x0) = ov;
}

// mean over spatial (vectorized): out[b*C + c], grid (C, B)
__global__ __launch_bounds__(256) void mean_kernel(
    const bf16* __restrict__ in, float* __restrict__ outp)
{
    const int Cc = gridDim.x;
    const int c = blockIdx.x, b = blockIdx.y;
    const bf16* p = in + ((long)b * Cc + c) * N4;
    float s = 0.f;
    for (int i = threadIdx.x * 8; i < N4; i += 2048) {
        bf16x8 v = *(const bf16x8*)(p + i);
        #pragma unroll
        for (int e = 0; e < 8; e++) s += (float)v[e];
    }
    #pragma unroll
    for (int o = 32; o; o >>= 1) s += __shfl_down(s, o, 64);
    __shared__ float red[4];
    if ((threadIdx.x & 63) == 0) red[threadIdx.x >> 6] = s;
    __syncthreads();
    if (threadIdx.x == 0)
        outp[b * Cc + c] = (red[0] + red[1] + red[2] + red[3]) * (1.0f / N4);
}

// ci1[b][o] = bias[o] + sum_i w[o][i]*tmean[b][i]  (w, bias f32)
__global__ __launch_bounds__(64) void ci1_kernel(
    const float* __restrict__ tmean, const float* __restrict__ wt,
    const float* __restrict__ bias, float* __restrict__ ci1v)
{
    const int b = blockIdx.x, o = threadIdx.x;
    float s = bias[o];
    for (int i = 0; i < 64; i++) s += wt[o * 64 + i] * tmean[b * 64 + i];
    ci1v[b * 64 + o] = s;
}

// g = t * ci1[b][c6] * u3  — 8 elems/thread
__global__ __launch_bounds__(256) void g_eltwise_kernel(
    const bf16* __restrict__ t, const float* __restrict__ ci1v,
    const bf16* __restrict__ u3, bf16* __restrict__ g)
{
    long idx = ((long)blockIdx.x * 256 + threadIdx.x) << 3;
    float s = ci1v[idx >> 12];
    bf16x8 tv = *(const bf16x8*)(t + idx);
    bf16x8 uv = *(const bf16x8*)(u3 + idx);
    bf16x8 ov;
    #pragma unroll
    for (int e = 0; e < 8; e++) ov[e] = (bf16)((float)tv[e] * s * (float)uv[e]);
    *(bf16x8*)(g + idx) = ov;
}

// g2 = gelu_exact(x1) * x2 — 8 elems/thread
__global__ __launch_bounds__(256) void gelu_mul_kernel(
    const bf16* __restrict__ dd, bf16* __restrict__ g2)
{
    long idx = ((long)blockIdx.x * 256 + threadIdx.x) << 3;
    int n = idx & 4095;
    long bc = idx >> 12;
    long b = bc / 96, cc = bc - b * 96;
    bf16x8 v1 = *(const bf16x8*)(dd + ((b * 192 + cc) << 12) + n);
    bf16x8 v2 = *(const bf16x8*)(dd + ((b * 192 + cc + 96) << 12) + n);
    bf16x8 ov;
    #pragma unroll
    for (int e = 0; e < 8; e++) {
        float x1 = (float)v1[e];
        float g = 0.5f * x1 * (1.0f + erff(x1 * 0.70710678118654752f));
        ov[e] = (bf16)(g * (float)v2[e]);
    }
    *(bf16x8*)(g2 + idx) = ov;
}

// at = (at + cmap)*sigmoid(smap) + convx*sigmoid(cm[b][c]) — 8 elems/thread
__global__ __launch_bounds__(256) void final_mix_kernel(
    bf16* __restrict__ at, const bf16* __restrict__ cmap,
    const bf16* __restrict__ smap, const bf16* __restrict__ convx,
    const float* __restrict__ cm)
{
    long idx = ((long)blockIdx.x * 256 + threadIdx.x) << 3;
    float g = 1.0f / (1.0f + expf(-cm[idx >> 12]));
    bf16x8 av = *(const bf16x8*)(at + idx);
    bf16x8 cv = *(const bf16x8*)(cmap + idx);
    bf16x8 sv = *(const bf16x8*)(smap + idx);
    bf16x8 xv = *(const bf16x8*)(convx + idx);
    bf16x8 ov;
    #pragma unroll
    for (int e = 0; e < 8; e++) {
        float a = (float)av[e] + (float)cv[e];
        float s = 1.0f / (1.0f + expf(-(float)sv[e]));
        ov[e] = (bf16)(a * s + (float)xv[e] * g);
    }
    *(bf16x8*)(at + idx) = ov;
}

// ---------------------------------------------------------------------------
extern "C" void kernel_launch(void* const* d_in, const int* in_sizes, int n_in,
                              void* d_out, int out_size, void* d_ws, size_t ws_size,
                              hipStream_t stream)
{
    const int B = 8, C = 384, N = N4, C6 = 64, C2 = 192, C4 = 96;

    char* wsp = (char*)d_ws;
    size_t off = 0;
    auto alloc = [&](size_t bytes) -> char* {
        char* p = wsp + off; off += (bytes + 255) & ~(size_t)255; return p;
    };

    // --- bf16 copies of the 9 MFMA-feeding tensors ---
    const int cvtIdx[9] = {0, 2, 3, 5, 9, 17, 19, 21, 25};
    bf16* cv[9];
    CvtArgs ca;
    long gpre = 0;
    for (int i = 0; i < 9; i++) {
        int ti = cvtIdx[i];
        cv[i] = (bf16*)alloc((size_t)in_sizes[ti] * 2);
        ca.src[i] = (const float*)d_in[ti];
        ca.dst[i] = cv[i];
        ca.gpre[i] = gpre;
        gpre += in_sizes[ti] >> 3;
    }
    ca.gpre[9] = gpre;
    cvt_kernel<<<(int)((gpre + 255) / 256), 256, 0, stream>>>(ca, gpre);

    const bf16* x_bf     = cv[0];
    const bf16* qkv_w    = cv[1];
    const bf16* proj_w   = cv[2];
    const bf16* dw1_w    = cv[3];
    const bf16* cp_in_w  = cv[4];
    const bf16* ci2c_w   = cv[5];
    const bf16* cp_out_w = cv[6];
    const bf16* sp_in_w  = cv[7];
    const bf16* sp_out_w = cv[8];

    // f32 direct-read small tensors
    const float* temp    = (const float*)d_in[1];
    const float* proj_b  = (const float*)d_in[4];
    const float* dw1_b   = (const float*)d_in[6];
    const float* dw2_w   = (const float*)d_in[7];
    const float* dw2_b   = (const float*)d_in[8];
    const float* cp_in_b = (const float*)d_in[10];
    const float* ci1_w   = (const float*)d_in[11];
    const float* ci1_b   = (const float*)d_in[12];
    const float* ci2a_w  = (const float*)d_in[13];
    const float* ci2a_b  = (const float*)d_in[14];
    const float* ci2b_w  = (const float*)d_in[15];
    const float* ci2b_b  = (const float*)d_in[16];
    const float* ci2c_b  = (const float*)d_in[18];
    const float* cp_out_b= (const float*)d_in[20];
    const float* sp_in_b = (const float*)d_in[22];
    const float* sp_dw_w = (const float*)d_in[23];
    const float* sp_dw_b = (const float*)d_in[24];
    const float* sp_out_b= (const float*)d_in[26];

    bf16*  QKV   = (bf16*) alloc((size_t)B * 3 * C * N * 2);
    bf16*  AT    = (bf16*) alloc((size_t)B * C * N * 2);
    bf16*  CONV1 = (bf16*) alloc((size_t)B * C * N * 2);
    bf16*  CONVX = (bf16*) alloc((size_t)B * C * N * 2);
    bf16*  CMAP  = (bf16*) alloc((size_t)B * C * N * 2);
    bf16*  T     = (bf16*) alloc((size_t)B * C6 * N * 2);
    bf16*  U1    = (bf16*) alloc((size_t)B * C6 * N * 2);
    bf16*  U2    = (bf16*) alloc((size_t)B * C6 * N * 2);
    bf16*  SP    = (bf16*) alloc((size_t)B * C2 * N * 2);
    bf16*  DDb   = (bf16*) alloc((size_t)B * C2 * N * 2);
    float* PART  = (float*)alloc((size_t)64 * 32 * 2304 * 4);
    float* ATTN  = (float*)alloc((size_t)64 * 2304 * 4);
    float* INVN  = (float*)alloc((size_t)B * 768 * 4);
    float* TMEAN = (float*)alloc((size_t)B * 64 * 4);
    float* CI1V  = (float*)alloc((size_t)B * 64 * 4);
    float* CMv   = (float*)alloc((size_t)B * C * 4);
    bf16* SMAP = CONV1;   // conv1 dead after dw2
    bf16* G2   = SP;      // sp dead after sp_dw
    bf16* U3   = U1;      // u1 dead after ci2b
    bf16* G    = U2;      // u2 dead after ci2c

    // 1. QKV = qkv_w @ x
    gemm128_kernel<<<8 * 32 * 9, 256, 0, stream>>>(
        qkv_w, x_bf, nullptr, QKV, 384, (long)C * N, (long)3 * C * N, 0);
    // 2. inverse L2 norms of q,k rows
    rownorm_kernel<<<dim3(768, 8), 256, 0, stream>>>(QKV, INVN);
    // 3-5. attention
    attn_logits_kernel<<<dim3(8, 64), 256, 0, stream>>>(QKV, PART);
    attn_softmax_kernel<<<64, 256, 0, stream>>>(PART, INVN, temp, ATTN);
    attn_apply_kernel<<<dim3(16, 64), 256, 0, stream>>>(ATTN, QKV, AT);
    // 6. conv1 = dw1 (1x1) on v
    gemm128_kernel<<<8 * 32 * 3, 256, 0, stream>>>(
        dw1_w, QKV + (size_t)2 * C * N, dw1_b, CONV1, 384, (long)3 * C * N, (long)C * N, 0);
    // 7. conv_x = depthwise 3x3
    dw_conv_kernel<3, 1, 1, 384><<<B * 384, 512, 0, stream>>>(CONV1, dw2_w, dw2_b, CONVX);
    // 8. t = cp_in (1x1) on attened
    gemm_bf16_kernel<<<8 * 64 * 1, 256, 0, stream>>>(
        cp_in_w, AT, cp_in_b, T, 384, (long)C * N, (long)C6 * N, 0);
    // 9-10. ci1
    mean_kernel<<<dim3(64, 8), 256, 0, stream>>>(T, TMEAN);
    ci1_kernel<<<8, 64, 0, stream>>>(TMEAN, ci1_w, ci1_b, CI1V);
    // 11-13. ci2 chain
    dw_conv_kernel<3, 1, 1, 64><<<B * 64, 512, 0, stream>>>(T, ci2a_w, ci2a_b, U1);
    dw_conv_kernel<7, 3, 9, 64><<<B * 64, 512, 0, stream>>>(U1, ci2b_w, ci2b_b, U2);
    gemm_bf16_kernel<<<8 * 64 * 1, 256, 0, stream>>>(
        ci2c_w, U2, ci2c_b, U3, 64, (long)C6 * N, (long)C6 * N, 0);
    // 14. g = t * ci1 * ci2
    g_eltwise_kernel<<<1024, 256, 0, stream>>>(T, CI1V, U3, G);
    // 15. channel_map = cp_out @ g
    gemm128_kernel<<<8 * 32 * 3, 256, 0, stream>>>(
        cp_out_w, G, cp_out_b, CMAP, 64, (long)C6 * N, (long)C * N, 0);
    // 16. cm
    mean_kernel<<<dim3(384, 8), 256, 0, stream>>>(CMAP, CMv);
    // 17. sp = sp_in @ conv_x
    gemm_bf16_kernel<<<8 * 64 * 3, 256, 0, stream>>>(
        sp_in_w, CONVX, sp_in_b, SP, 384, (long)C * N, (long)C2 * N, 0);
    // 18. d = depthwise 3x3 on sp
    dw_conv_kernel<3, 1, 1, 192><<<B * 192, 512, 0, stream>>>(SP, sp_dw_w, sp_dw_b, DDb);
    // 19. g2 = gelu(x1)*x2
    gelu_mul_kernel<<<1536, 256, 0, stream>>>(DDb, G2);
    // 20. spatial_map = sp_out @ g2
    gemm128_kernel<<<8 * 32 * 3, 256, 0, stream>>>(
        sp_out_w, G2, sp_out_b, SMAP, 96, (long)C4 * N, (long)C * N, 0);
    // 21. final mix
    final_mix_kernel<<<6144, 256, 0, stream>>>(AT, CMAP, SMAP, CONVX, CMv);
    // 22. out = proj_w @ at + proj_b   -> f32 output
    gemm128_kernel<<<8 * 32 * 3, 256, 0, stream>>>(
        proj_w, AT, proj_b, d_out, 384, (long)C * N, (long)C * N, 1);
}